// Round 1
// baseline (349.445 us; speedup 1.0000x reference)
//
#include <hip/hip_runtime.h>

// Aggregation: out[n,ch,y,x] = sum_{i,j in 3x3} in_pad[n,ch,y+i-1,x+j-1] * w[n, ch%64, 3i+j, y*64+x]
// N=16, C_X=512, C_W=64, groups=8, H=W=64, pad=1, stride=1, dil=1.
// Memory-bound: ideal traffic ~419 MB -> ~67 us @ 6.3 TB/s.

#define HW 4096   // 64*64 plane elements
#define CX 512
#define CW 64
#define NGRP 8

__global__ __launch_bounds__(256) void agg_kernel(const float* __restrict__ in,
                                                  const float* __restrict__ wgt,
                                                  float* __restrict__ out)
{
    // blockIdx.x = ((n*64 + c) * 4 + yt), 4096 blocks
    const int bid = blockIdx.x;
    const int yt  = bid & 3;
    const int nc  = bid >> 2;
    const int c   = nc & 63;
    const int n   = nc >> 6;

    const int tid = threadIdx.x;
    const int qx  = tid & 15;        // 16 quads cover x=0..63
    const int yl  = tid >> 4;        // 0..15 rows per block
    const int y   = yt * 16 + yl;
    const int x0  = qx * 4;

    // ---- load the 9 per-pixel weights once (float4 over x) ----
    const float* wbase = wgt + ((size_t)(n * CW + c) * 9) * HW + y * 64 + x0;
    float4 w[9];
#pragma unroll
    for (int t = 0; t < 9; ++t)
        w[t] = *reinterpret_cast<const float4*>(wbase + (size_t)t * HW);

    const size_t nc_off = (size_t)n * CX * HW + (size_t)c * HW;   // (n, ch=c) plane
    const float* inb  = in  + nc_off;
    float*       outb = out + nc_off + (size_t)y * 64 + x0;

#pragma unroll
    for (int g = 0; g < NGRP; ++g) {
        const float* plane = inb + (size_t)g * CW * HW;
        float4 acc = make_float4(0.f, 0.f, 0.f, 0.f);
#pragma unroll
        for (int i = 0; i < 3; ++i) {
            const int ry = y + i - 1;
            float4 v;
            float lft, rgt;
            if (ry >= 0 && ry < 64) {
                const float* row = plane + ry * 64;
                v   = *reinterpret_cast<const float4*>(row + x0);
                lft = (x0 > 0)      ? row[x0 - 1] : 0.f;
                rgt = (x0 + 4 < 64) ? row[x0 + 4] : 0.f;
            } else {
                v = make_float4(0.f, 0.f, 0.f, 0.f);
                lft = 0.f; rgt = 0.f;
            }
            // shifted views for taps j=0 (left) and j=2 (right)
            const float4 lv = make_float4(lft, v.x, v.y, v.z);
            const float4 rv = make_float4(v.y, v.z, v.w, rgt);
            const float4 w0 = w[i * 3 + 0];
            const float4 w1 = w[i * 3 + 1];
            const float4 w2 = w[i * 3 + 2];
            acc.x += lv.x * w0.x + v.x * w1.x + rv.x * w2.x;
            acc.y += lv.y * w0.y + v.y * w1.y + rv.y * w2.y;
            acc.z += lv.z * w0.z + v.z * w1.z + rv.z * w2.z;
            acc.w += lv.w * w0.w + v.w * w1.w + rv.w * w2.w;
        }
        *reinterpret_cast<float4*>(outb + (size_t)g * CW * HW) = acc;
    }
}

extern "C" void kernel_launch(void* const* d_in, const int* in_sizes, int n_in,
                              void* d_out, int out_size, void* d_ws, size_t ws_size,
                              hipStream_t stream) {
    const float* in  = (const float*)d_in[0];
    const float* wg  = (const float*)d_in[1];
    float*       out = (float*)d_out;
    // 16 n * 64 c * 4 ytiles = 4096 blocks, 256 threads each
    agg_kernel<<<4096, 256, 0, stream>>>(in, wg, out);
}

// Round 2
// 334.719 us; speedup vs baseline: 1.0440x; 1.0440x over previous
//
#include <hip/hip_runtime.h>

// Aggregation: out[n,ch,y,x] = sum_{i,j in 3x3} in_pad[n,ch,y+i-1,x+j-1] * w[n, ch%64, 3i+j, y*64+x]
// N=16, C_X=512, C_W=64, groups=8, H=W=64, pad=1.
// Latency-bound fix (R2): 3 uniform float4 loads/group (edges via shuffles),
// depth-1 software pipeline over groups, per-row partial accumulators.

#define HW 4096   // 64*64
#define CX 512
#define CW 64
#define NGRP 8

__global__ __launch_bounds__(256) void agg_kernel(const float* __restrict__ in,
                                                  const float* __restrict__ wgt,
                                                  float* __restrict__ out)
{
    // blockIdx.x = ((n*64 + c) * 4 + yt), 4096 blocks
    const int bid = blockIdx.x;
    const int yt  = bid & 3;
    const int nc  = bid >> 2;
    const int c   = nc & 63;
    const int n   = nc >> 6;

    const int tid = threadIdx.x;
    const int qx  = tid & 15;        // 16 quads cover x=0..63 (one row per 16-lane group)
    const int yl  = tid >> 4;        // 16 rows per block
    const int y   = yt * 16 + yl;
    const int x0  = qx * 4;

    // ---- per-pixel weights, loaded once (9 x float4) ----
    const float* wbase = wgt + ((size_t)(n * CW + c) * 9) * HW + y * 64 + x0;
    float4 w[9];
#pragma unroll
    for (int t = 0; t < 9; ++t)
        w[t] = *reinterpret_cast<const float4*>(wbase + (size_t)t * HW);

    const size_t nc_off = (size_t)n * CX * HW + (size_t)c * HW;
    const float* inb  = in  + nc_off + (size_t)y * 64 + x0;   // center element of this quad
    float*       outb = out + nc_off + (size_t)y * 64 + x0;

    const bool has_top = (y > 0);
    const bool has_bot = (y < 63);
    const float4 zero = make_float4(0.f, 0.f, 0.f, 0.f);

    // double-buffered row registers (indices compile-time after full unroll)
    float4 r0[2], r1[2], r2[2];

    // prefetch group 0
    {
        const float* p = inb;
        r1[0] = *reinterpret_cast<const float4*>(p);
        r0[0] = has_top ? *reinterpret_cast<const float4*>(p - 64) : zero;
        r2[0] = has_bot ? *reinterpret_cast<const float4*>(p + 64) : zero;
    }

#pragma unroll
    for (int g = 0; g < NGRP; ++g) {
        const int cur = g & 1;
        const int nxt = cur ^ 1;
        if (g < NGRP - 1) {   // issue next group's loads before computing current
            const float* p = inb + (size_t)(g + 1) * CW * HW;
            r1[nxt] = *reinterpret_cast<const float4*>(p);
            r0[nxt] = has_top ? *reinterpret_cast<const float4*>(p - 64) : zero;
            r2[nxt] = has_bot ? *reinterpret_cast<const float4*>(p + 64) : zero;
        }

        // ---- compute current group: 3 rows, independent partial accumulators ----
        float4 a0, a1, a2;
        {
            const float4 v = r0[cur];
            float lft = __shfl_up(v.w, 1, 16);   lft = (qx > 0)  ? lft : 0.f;
            float rgt = __shfl_down(v.x, 1, 16); rgt = (qx < 15) ? rgt : 0.f;
            const float4 w0 = w[0], w1 = w[1], w2 = w[2];
            a0.x = fmaf(lft, w0.x, fmaf(v.x, w1.x, v.y * w2.x));
            a0.y = fmaf(v.x, w0.y, fmaf(v.y, w1.y, v.z * w2.y));
            a0.z = fmaf(v.y, w0.z, fmaf(v.z, w1.z, v.w * w2.z));
            a0.w = fmaf(v.z, w0.w, fmaf(v.w, w1.w, rgt * w2.w));
        }
        {
            const float4 v = r1[cur];
            float lft = __shfl_up(v.w, 1, 16);   lft = (qx > 0)  ? lft : 0.f;
            float rgt = __shfl_down(v.x, 1, 16); rgt = (qx < 15) ? rgt : 0.f;
            const float4 w0 = w[3], w1 = w[4], w2 = w[5];
            a1.x = fmaf(lft, w0.x, fmaf(v.x, w1.x, v.y * w2.x));
            a1.y = fmaf(v.x, w0.y, fmaf(v.y, w1.y, v.z * w2.y));
            a1.z = fmaf(v.y, w0.z, fmaf(v.z, w1.z, v.w * w2.z));
            a1.w = fmaf(v.z, w0.w, fmaf(v.w, w1.w, rgt * w2.w));
        }
        {
            const float4 v = r2[cur];
            float lft = __shfl_up(v.w, 1, 16);   lft = (qx > 0)  ? lft : 0.f;
            float rgt = __shfl_down(v.x, 1, 16); rgt = (qx < 15) ? rgt : 0.f;
            const float4 w0 = w[6], w1 = w[7], w2 = w[8];
            a2.x = fmaf(lft, w0.x, fmaf(v.x, w1.x, v.y * w2.x));
            a2.y = fmaf(v.x, w0.y, fmaf(v.y, w1.y, v.z * w2.y));
            a2.z = fmaf(v.y, w0.z, fmaf(v.z, w1.z, v.w * w2.z));
            a2.w = fmaf(v.z, w0.w, fmaf(v.w, w1.w, rgt * w2.w));
        }

        float4 acc;
        acc.x = a0.x + a1.x + a2.x;
        acc.y = a0.y + a1.y + a2.y;
        acc.z = a0.z + a1.z + a2.z;
        acc.w = a0.w + a1.w + a2.w;

        *reinterpret_cast<float4*>(outb + (size_t)g * CW * HW) = acc;
    }
}

extern "C" void kernel_launch(void* const* d_in, const int* in_sizes, int n_in,
                              void* d_out, int out_size, void* d_ws, size_t ws_size,
                              hipStream_t stream) {
    const float* in  = (const float*)d_in[0];
    const float* wg  = (const float*)d_in[1];
    float*       out = (float*)d_out;
    agg_kernel<<<4096, 256, 0, stream>>>(in, wg, out);
}